// Round 4
// baseline (3341.162 us; speedup 1.0000x reference)
//
#include <hip/hip_runtime.h>
#include <hip/hip_bf16.h>
#include <math.h>

typedef __bf16 bf16x8 __attribute__((ext_vector_type(8)));
typedef __bf16 bf16x4 __attribute__((ext_vector_type(4)));
typedef float f32x4 __attribute__((ext_vector_type(4)));

#define S_LEN 128
#define BATCH 32
#define E2C 1024
#define DH 512
#define AH 32
#define EMBD 256
#define VOC 32000
#define TMAX 48
#define LCHN 250     /* logits chunks: 128 vocab rows each */
#define CTXB 64      /* context blocks: 2 per batch, 512 elems each */

#define MFMA16(a, b, c) __builtin_amdgcn_mfma_f32_16x16x32_bf16((a), (b), (c), 0, 0, 0)

// ---- workspace layout (bytes) ----
#define OFF_HF0   0
#define OFF_HH0   65536
#define OFF_HL0   98304
#define OFF_HF1   131072
#define OFF_HH1   196608
#define OFF_HL1   229376
#define OFF_XH    262144            /* [32][1024] bf16 context hi */
#define OFF_XL    344064            /* [32][1024] bf16 context lo */
#define OFF_ENCW1 425984
#define OFF_PVAL  950272            /* 32 x 256 f32 */
#define OFF_PIDX  983040            /* 32 x 256 i32 */
#define OFF_WOH   1015808
#define OFF_WOL   33783808
#define OFF_WIHH  66551808
#define OFF_WIHL  70483968
#define OFF_WHHH  74416128
#define OFF_WHHL  75988992
#define WS_REQ    77561856ULL

// Split 8 consecutive f32 into bf16 hi + bf16 lo (x = hi + lo + O(2^-18 x)).
__device__ __forceinline__ void split8(const float* __restrict__ p,
                                       bf16x8& hi, bf16x8& lo) {
  const f32x4 v0 = *(const f32x4*)p;
  const f32x4 v1 = *(const f32x4*)(p + 4);
  float t[8] = {v0[0], v0[1], v0[2], v0[3], v1[0], v1[1], v1[2], v1[3]};
  #pragma unroll
  for (int i = 0; i < 8; i++) {
    const __bf16 h = (__bf16)t[i];
    hi[i] = h;
    lo[i] = (__bf16)(t[i] - (float)h);
  }
}

// ---------------------------------------------------------------------------
// K_init: zero the h-state block (hf0|hh0|hl0 = 131072 B = 32768 u32).
// ---------------------------------------------------------------------------
__global__ __launch_bounds__(256) void k_init(unsigned int* __restrict__ p) {
  p[blockIdx.x * 256 + threadIdx.x] = 0u;
}

// ---------------------------------------------------------------------------
// K0: encW1[s,b,j] = sum_k enc[s,b,k] * W1[j, DH+k]   (hoisted out of t-loop)
// ---------------------------------------------------------------------------
__global__ __launch_bounds__(256) void k_encw1(const float* __restrict__ enc,
                                               const float* __restrict__ W1,
                                               float* __restrict__ encW1) {
  __shared__ float el[E2C];
  __shared__ float red[256];
  const int tid = threadIdx.x;
  const int blk = blockIdx.x;                       // s*BATCH + b
  for (int i = 0; i < 4; i++)
    el[tid + i * 256] = enc[(size_t)blk * E2C + tid + i * 256];
  __syncthreads();
  const int j = tid >> 3, c = tid & 7;
  const float* wrow = W1 + (size_t)j * (DH + E2C) + DH;
  float p = 0.f;
  for (int k = c * 128; k < c * 128 + 128; k++) p += el[k] * wrow[k];
  red[tid] = p;
  __syncthreads();
  if (c < 4) red[tid] += red[tid + 4];
  __syncthreads();
  if (c < 2) red[tid] += red[tid + 2];
  __syncthreads();
  if (c == 0) encW1[(size_t)blk * AH + j] = red[tid] + red[tid + 1];
}

// ---------------------------------------------------------------------------
// K_split4: one-time f32 -> (bf16 hi, bf16 lo) split, 4 elements/thread.
// ---------------------------------------------------------------------------
__global__ __launch_bounds__(256) void k_split4(const float* __restrict__ src,
                                                __bf16* __restrict__ dh,
                                                __bf16* __restrict__ dl, int n4) {
  const int i = blockIdx.x * 256 + threadIdx.x;
  if (i >= n4) return;
  const f32x4 v = ((const f32x4*)src)[i];
  bf16x4 h4, l4;
  #pragma unroll
  for (int j = 0; j < 4; j++) {
    const float x = v[j];
    const __bf16 h = (__bf16)x;
    h4[j] = h;
    l4[j] = (__bf16)(x - (float)h);
  }
  *(bf16x4*)(dh + (size_t)i * 4) = h4;
  *(bf16x4*)(dl + (size_t)i * 4) = l4;
}

// ---------------------------------------------------------------------------
// ctx_block: attention context for one (batch, half) pair; 512 threads.
//   bc = batch*2 + part. Phases B/C identical math to the verified r3 k_attn
//   (bit-exact); phase D computes 512 context elements (1/thread).
// ---------------------------------------------------------------------------
__device__ __forceinline__ void ctx_block(int bc, int tid,
    const float* __restrict__ enc,
    const float* __restrict__ W1, const float* __restrict__ b1,
    const float* __restrict__ W2, const float* __restrict__ b2,
    const float* __restrict__ encW1, const float* __restrict__ hf,
    __bf16* __restrict__ xh, __bf16* __restrict__ xl,
    float* hs, float* hw, float* sc, float* red) {
  const int b = bc >> 1;
  const int part = bc & 1;

  // Phase B: hW1[j] = h[b,:] . W1[j,0:DH] + b1[j]  (256 workers, as r3)
  if (tid < 256) {
    hs[tid] = hf[b * DH + tid];
    hs[tid + 256] = hf[b * DH + tid + 256];
  }
  __syncthreads();
  if (tid < 256) {
    const int j = tid >> 3, c = tid & 7;
    const float* wrow = W1 + (size_t)j * (DH + E2C);
    float p = 0.f;
    for (int k = c * 64; k < c * 64 + 64; k++) p += hs[k] * wrow[k];
    red[tid] = p;
  }
  __syncthreads();
  if (tid < 256 && (tid & 7) < 4) red[tid] += red[tid + 4];
  __syncthreads();
  if (tid < 256 && (tid & 7) < 2) red[tid] += red[tid + 2];
  __syncthreads();
  if (tid < 256 && (tid & 7) == 0) hw[tid >> 3] = red[tid] + red[tid + 1] + b1[tid >> 3];
  __syncthreads();

  // Phase C: scores + softmax over S (identical to r3)
  float ex = 0.f;
  if (tid < S_LEN) {
    const float* ew = encW1 + ((size_t)tid * BATCH + b) * AH;
    float sum = b2[0];
    #pragma unroll
    for (int j = 0; j < AH; j++) {
      const float v = ew[j] + hw[j];
      sum += fmaxf(v, 0.f) * W2[j];
    }
    sc[tid] = sum;
  }
  __syncthreads();
  if (tid < 128) red[tid] = sc[tid];
  __syncthreads();
  for (int off = 64; off >= 1; off >>= 1) {
    if (tid < off) red[tid] = fmaxf(red[tid], red[tid + off]);
    __syncthreads();
  }
  const float mx = red[0];
  __syncthreads();
  if (tid < 128) { ex = expf(sc[tid] - mx); red[tid] = ex; }
  __syncthreads();
  for (int off = 64; off >= 1; off >>= 1) {
    if (tid < off) red[tid] += red[tid + off];
    __syncthreads();
  }
  const float ssum = red[0];
  if (tid < 128) sc[tid] = ex / ssum;
  __syncthreads();

  // Phase D: context half [part*512, part*512+512), 1 element/thread
  const int e0 = part * 512 + tid;
  float aa = 0.f;
  for (int s = 0; s < S_LEN; s++)
    aa += sc[s] * enc[((size_t)s * BATCH + b) * E2C + e0];
  const __bf16 ch = (__bf16)aa;
  xh[b * 1024 + e0] = ch;
  xl[b * 1024 + e0] = (__bf16)(aa - (float)ch);
}

// ---------------------------------------------------------------------------
// K_ctx0: initial context (t=0, h=0). Grid = 64 x 512.
// ---------------------------------------------------------------------------
__global__ __launch_bounds__(512) void k_ctx0(
    const float* __restrict__ enc,
    const float* __restrict__ W1, const float* __restrict__ b1,
    const float* __restrict__ W2, const float* __restrict__ b2,
    const float* __restrict__ encW1, const float* __restrict__ hf,
    __bf16* __restrict__ xh, __bf16* __restrict__ xl) {
  __shared__ float hs[DH];
  __shared__ float hw[AH];
  __shared__ float sc[S_LEN];
  __shared__ float red[256];
  ctx_block(blockIdx.x, threadIdx.x, enc, W1, b1, W2, b2, encW1, hf, xh, xl,
            hs, hw, sc, red);
}

// ---------------------------------------------------------------------------
// K2: GRU cell. Grid = 32 blocks x 256 (16 d-rows each, K-split-4 over waves).
// Prologue: final argmax over pval/pidx (prev step) -> token ids (LDS);
// the embedding K-slab (i=8,9) is loaded directly from emb with split8 —
// bit-identical values to the old xh/xl emb staging.
// ---------------------------------------------------------------------------
template<bool PRE>
__global__ __launch_bounds__(256) void k_gru(int t,
    const int* __restrict__ sos, const float* __restrict__ emb,
    const float* __restrict__ pval, const int* __restrict__ pidx,
    const __bf16* __restrict__ xh, const __bf16* __restrict__ xl,
    const float* __restrict__ Wih, const float* __restrict__ bih,
    const float* __restrict__ Whh, const float* __restrict__ bhh,
    const __bf16* __restrict__ Wihh, const __bf16* __restrict__ Wihl,
    const __bf16* __restrict__ Whhh, const __bf16* __restrict__ Whhl,
    const float* __restrict__ hf_in, const __bf16* __restrict__ hh_in,
    const __bf16* __restrict__ hl_in,
    float* __restrict__ hf_out, __bf16* __restrict__ hh_out,
    __bf16* __restrict__ hl_out) {
  __shared__ float lds[4][8][256];
  __shared__ int ids[32];
  const int tid = threadIdx.x;

  // ---- prologue: token ids for this step ----
  if (t == 0) {
    if (tid < 32) {
      int id = sos[0];
      if (id < 0 || id >= VOC) id = 0;
      ids[tid] = id;
    }
  } else {
    float* sv = &lds[0][0][0];
    int*   si = (int*)&lds[1][0][0];
    const int b = tid >> 3, c0 = tid & 7;
    float bv = -INFINITY; int bi = 0x7fffffff;
    for (int c = c0; c < LCHN; c += 8) {
      const float v = pval[b * 256 + c]; const int ix = pidx[b * 256 + c];
      if (v > bv || (v == bv && ix < bi)) { bv = v; bi = ix; }
    }
    sv[tid] = bv; si[tid] = bi;
    __syncthreads();
    for (int off = 4; off >= 1; off >>= 1) {
      if (c0 < off) {
        const float ov = sv[tid + off]; const int oi = si[tid + off];
        if (ov > sv[tid] || (ov == sv[tid] && oi < si[tid])) { sv[tid] = ov; si[tid] = oi; }
      }
      __syncthreads();
    }
    if (c0 == 0) {
      int id = si[tid];
      if (id < 0 || id >= VOC) id = 0;
      ids[b] = id;
    }
  }
  __syncthreads();

  const int wv = tid >> 6;
  const int lane = tid & 63;
  const int q = lane >> 4;
  const int ln = lane & 15;
  const int d = blockIdx.x * 16 + ln;          // weight row (n index)
  const int id0 = ids[ln];
  const int id1 = ids[16 + ln];

  f32x4 acc[4][2];                             // t: 0=r 1=z 2=n_i 3=n_h; [mt]
  const f32x4 z4 = {0.f, 0.f, 0.f, 0.f};
  #pragma unroll
  for (int tt = 0; tt < 4; tt++) { acc[tt][0] = z4; acc[tt][1] = z4; }

  #pragma unroll
  for (int i = 0; i < 14; i++) {
    const int ka = wv * 32 + i * 128 + q * 8;
    bf16x8 ah0, al0, ah1, al1;
    if (i < 8) {                               // context from x
      ah0 = *(const bf16x8*)(xh + ln * 1024 + ka);
      ah1 = *(const bf16x8*)(xh + (16 + ln) * 1024 + ka);
      al0 = *(const bf16x8*)(xl + ln * 1024 + ka);
      al1 = *(const bf16x8*)(xl + (16 + ln) * 1024 + ka);
    } else if (i < 10) {                       // embedding, direct from table
      const int kb = ka - 1024;
      split8(emb + (size_t)id0 * EMBD + kb, ah0, al0);
      split8(emb + (size_t)id1 * EMBD + kb, ah1, al1);
    } else {                                   // hidden state
      const int kb = ka - 1280;
      ah0 = *(const bf16x8*)(hh_in + ln * 512 + kb);
      ah1 = *(const bf16x8*)(hh_in + (16 + ln) * 512 + kb);
      al0 = *(const bf16x8*)(hl_in + ln * 512 + kb);
      al1 = *(const bf16x8*)(hl_in + (16 + ln) * 512 + kb);
    }
    #pragma unroll
    for (int g = 0; g < 3; g++) {
      bf16x8 bh, bl;
      if (PRE) {
        if (i < 10) {
          bh = *(const bf16x8*)(Wihh + (size_t)(g * 512 + d) * 1280 + ka);
          bl = *(const bf16x8*)(Wihl + (size_t)(g * 512 + d) * 1280 + ka);
        } else {
          bh = *(const bf16x8*)(Whhh + (size_t)(g * 512 + d) * 512 + (ka - 1280));
          bl = *(const bf16x8*)(Whhl + (size_t)(g * 512 + d) * 512 + (ka - 1280));
        }
      } else {
        if (i < 10) split8(Wih + (size_t)(g * 512 + d) * 1280 + ka, bh, bl);
        else        split8(Whh + (size_t)(g * 512 + d) * 512 + (ka - 1280), bh, bl);
      }
      const int tt = (g < 2) ? g : ((i < 10) ? 2 : 3);
      acc[tt][0] = MFMA16(ah0, bh, acc[tt][0]);
      acc[tt][0] = MFMA16(al0, bh, acc[tt][0]);
      acc[tt][0] = MFMA16(ah0, bl, acc[tt][0]);
      acc[tt][1] = MFMA16(ah1, bh, acc[tt][1]);
      acc[tt][1] = MFMA16(al1, bh, acc[tt][1]);
      acc[tt][1] = MFMA16(ah1, bl, acc[tt][1]);
    }
  }

  // stage per-wave partials: tile tt2 = tt*2+mt, elem = row*16 + col
  #pragma unroll
  for (int tt = 0; tt < 4; tt++)
    #pragma unroll
    for (int mt = 0; mt < 2; mt++)
      #pragma unroll
      for (int r = 0; r < 4; r++)
        lds[wv][tt * 2 + mt][(q * 4 + r) * 16 + ln] = acc[tt][mt][r];
  __syncthreads();
  for (int idx = tid; idx < 8 * 256; idx += 256) {
    const int tt = idx >> 8, e = idx & 255;
    lds[0][tt][e] += lds[1][tt][e] + lds[2][tt][e] + lds[3][tt][e];
  }
  __syncthreads();

  // epilogue: (b, dd) pairs; D row = batch, col = d
  for (int u = tid; u < 512; u += 256) {
    const int b = u >> 4, dd = u & 15;
    const int mt = b >> 4;
    const int e = (b & 15) * 16 + dd;
    const int dg = blockIdx.x * 16 + dd;
    const float rp  = lds[0][0 * 2 + mt][e] + bih[dg]        + bhh[dg];
    const float zp  = lds[0][1 * 2 + mt][e] + bih[DH + dg]   + bhh[DH + dg];
    const float gin = lds[0][2 * 2 + mt][e] + bih[2 * DH + dg];
    const float ghn = lds[0][3 * 2 + mt][e] + bhh[2 * DH + dg];
    const float rg = 1.f / (1.f + expf(-rp));
    const float zg = 1.f / (1.f + expf(-zp));
    const float ng = tanhf(gin + rg * ghn);
    const float hp = hf_in[b * DH + dg];
    const float hn = (1.f - zg) * ng + zg * hp;
    hf_out[b * DH + dg] = hn;
    const __bf16 hi = (__bf16)hn;
    hh_out[b * DH + dg] = hi;
    hl_out[b * DH + dg] = (__bf16)(hn - (float)hi);
  }
}

// ---------------------------------------------------------------------------
// K3: merged logits + next-step context. Grid = 314 x 512.
//   blocks 0..249  : logits (128 vocab rows; 8 waves, 1 row-tile each),
//                    NT stores for out, per-chunk argmax partials.
//   blocks 250..313: context(t+1) (depends only on h(t+1), like logits).
// ---------------------------------------------------------------------------
template<bool PRE>
__global__ __launch_bounds__(512) void k_logctx(
    const float* __restrict__ enc,
    const float* __restrict__ W1, const float* __restrict__ b1,
    const float* __restrict__ W2, const float* __restrict__ b2,
    const float* __restrict__ encW1,
    const float* __restrict__ Wo, const float* __restrict__ bo,
    const __bf16* __restrict__ Woh, const __bf16* __restrict__ Wol,
    const float* __restrict__ hf, const __bf16* __restrict__ hh,
    const __bf16* __restrict__ hl,
    float* __restrict__ outp, float* __restrict__ pval, int* __restrict__ pidx,
    __bf16* __restrict__ xh, __bf16* __restrict__ xl) {
  __shared__ union {
    struct { float hs[DH]; float hw[AH]; float sc[S_LEN]; float red[256]; } c;
    struct { float lv[256]; int li[256]; } l;
  } sm;
  const int tid = threadIdx.x;
  const int blk = blockIdx.x;

  if (blk >= LCHN) {                 // ---- context path ----
    ctx_block(blk - LCHN, tid, enc, W1, b1, W2, b2, encW1, hf, xh, xl,
              sm.c.hs, sm.c.hw, sm.c.sc, sm.c.red);
    return;
  }

  // ---- logits path ----
  const int w = tid >> 6;
  const int lane = tid & 63;
  const int quad = lane >> 4;
  const int ln = lane & 15;
  const int v0 = blk * 128;
  const int vr = v0 + w * 16 + ln;

  f32x4 acc[2];
  const f32x4 z4 = {0.f, 0.f, 0.f, 0.f};
  acc[0] = z4; acc[1] = z4;

  const __bf16* wrh = Woh + (size_t)vr * 512;
  const __bf16* wrl = Wol + (size_t)vr * 512;
  const float*  wrf = Wo  + (size_t)vr * 512;

  #pragma unroll 2
  for (int kk = 0; kk < 512; kk += 32) {
    const int ka = kk + quad * 8;
    const bf16x8 fh0 = *(const bf16x8*)(hh + ln * 512 + ka);
    const bf16x8 fh1 = *(const bf16x8*)(hh + (16 + ln) * 512 + ka);
    const bf16x8 fl0 = *(const bf16x8*)(hl + ln * 512 + ka);
    const bf16x8 fl1 = *(const bf16x8*)(hl + (16 + ln) * 512 + ka);
    bf16x8 bh, bl;
    if (PRE) {
      bh = *(const bf16x8*)(wrh + ka);
      bl = *(const bf16x8*)(wrl + ka);
    } else {
      split8(wrf + ka, bh, bl);
    }
    acc[0] = MFMA16(fh0, bh, acc[0]);
    acc[0] = MFMA16(fl0, bh, acc[0]);
    acc[0] = MFMA16(fh0, bl, acc[0]);
    acc[1] = MFMA16(fh1, bh, acc[1]);
    acc[1] = MFMA16(fl1, bh, acc[1]);
    acc[1] = MFMA16(fh1, bl, acc[1]);
  }

  float bv[2][4]; int bi[2][4];
  const float bias = bo[vr];
  #pragma unroll
  for (int mt = 0; mt < 2; mt++) {
    #pragma unroll
    for (int r = 0; r < 4; r++) {
      const float val = acc[mt][r] + bias;
      const int b = mt * 16 + quad * 4 + r;
      __builtin_nontemporal_store(val, &outp[(size_t)b * VOC + vr]);
      bv[mt][r] = val; bi[mt][r] = vr;
    }
  }
  // reduce over the 16 lanes (ln) holding different v
  #pragma unroll
  for (int m = 1; m < 16; m <<= 1) {
    #pragma unroll
    for (int mt = 0; mt < 2; mt++) {
      #pragma unroll
      for (int r = 0; r < 4; r++) {
        const float ov = __shfl_xor(bv[mt][r], m, 64);
        const int oi = __shfl_xor(bi[mt][r], m, 64);
        if (ov > bv[mt][r] || (ov == bv[mt][r] && oi < bi[mt][r])) {
          bv[mt][r] = ov; bi[mt][r] = oi;
        }
      }
    }
  }
  if (ln == 0) {
    #pragma unroll
    for (int mt = 0; mt < 2; mt++)
      for (int r = 0; r < 4; r++) {
        const int b = mt * 16 + quad * 4 + r;
        sm.l.lv[w * 32 + b] = bv[mt][r];
        sm.l.li[w * 32 + b] = bi[mt][r];
      }
  }
  __syncthreads();
  if (tid < 32) {
    float bbv = sm.l.lv[tid]; int bbi = sm.l.li[tid];
    for (int w2 = 1; w2 < 8; w2++) {           // ascending wave -> ascending v
      const float ov = sm.l.lv[w2 * 32 + tid]; const int oi = sm.l.li[w2 * 32 + tid];
      if (ov > bbv || (ov == bbv && oi < bbi)) { bbv = ov; bbi = oi; }
    }
    pval[tid * 256 + blk] = bbv;
    pidx[tid * 256 + blk] = bbi;
  }
}

// ---------------------------------------------------------------------------
extern "C" void kernel_launch(void* const* d_in, const int* in_sizes, int n_in,
                              void* d_out, int out_size, void* d_ws, size_t ws_size,
                              hipStream_t stream) {
  const float* enc = (const float*)d_in[0];
  const int* sos = (const int*)d_in[2];
  const float* emb = (const float*)d_in[3];
  const float* W1 = (const float*)d_in[4];
  const float* b1 = (const float*)d_in[5];
  const float* W2 = (const float*)d_in[6];
  const float* b2 = (const float*)d_in[7];
  const float* Wih = (const float*)d_in[8];
  const float* bih = (const float*)d_in[9];
  const float* Whh = (const float*)d_in[10];
  const float* bhh = (const float*)d_in[11];
  const float* Wo = (const float*)d_in[12];
  const float* bo = (const float*)d_in[13];

  char* ws = (char*)d_ws;
  float* hf[2]  = {(float*)(ws + OFF_HF0),  (float*)(ws + OFF_HF1)};
  __bf16* hh[2] = {(__bf16*)(ws + OFF_HH0), (__bf16*)(ws + OFF_HH1)};
  __bf16* hl[2] = {(__bf16*)(ws + OFF_HL0), (__bf16*)(ws + OFF_HL1)};
  __bf16* xh = (__bf16*)(ws + OFF_XH);
  __bf16* xl = (__bf16*)(ws + OFF_XL);
  float* encW1 = (float*)(ws + OFF_ENCW1);
  float* pval = (float*)(ws + OFF_PVAL);
  int* pidx = (int*)(ws + OFF_PIDX);
  __bf16* Woh  = (__bf16*)(ws + OFF_WOH);
  __bf16* Wol  = (__bf16*)(ws + OFF_WOL);
  __bf16* Wihh = (__bf16*)(ws + OFF_WIHH);
  __bf16* Wihl = (__bf16*)(ws + OFF_WIHL);
  __bf16* Whhh = (__bf16*)(ws + OFF_WHHH);
  __bf16* Whhl = (__bf16*)(ws + OFF_WHHL);

  k_init<<<128, 256, 0, stream>>>((unsigned int*)ws);   // h state = 0
  k_encw1<<<S_LEN * BATCH, 256, 0, stream>>>(enc, W1, encW1);

  float* out = (float*)d_out;
  const bool pre = (ws_size >= WS_REQ);
  if (pre) {
    k_split4<<<16000, 256, 0, stream>>>(Wo,  Woh,  Wol,  4096000);
    k_split4<<<1920,  256, 0, stream>>>(Wih, Wihh, Wihl, 491520);
    k_split4<<<768,   256, 0, stream>>>(Whh, Whhh, Whhl, 196608);
  }
  k_ctx0<<<CTXB, 512, 0, stream>>>(enc, W1, b1, W2, b2, encW1, hf[0], xh, xl);

  for (int t = 0; t < TMAX; t++) {
    const int p = t & 1;
    if (pre) {
      k_gru<true><<<32, 256, 0, stream>>>(t, sos, emb, pval, pidx, xh, xl,
                                          Wih, bih, Whh, bhh,
                                          Wihh, Wihl, Whhh, Whhl,
                                          hf[p], hh[p], hl[p],
                                          hf[p ^ 1], hh[p ^ 1], hl[p ^ 1]);
      k_logctx<true><<<LCHN + CTXB, 512, 0, stream>>>(enc, W1, b1, W2, b2, encW1,
                                          Wo, bo, Woh, Wol,
                                          hf[p ^ 1], hh[p ^ 1], hl[p ^ 1],
                                          out + (size_t)t * BATCH * VOC,
                                          pval, pidx, xh, xl);
    } else {
      k_gru<false><<<32, 256, 0, stream>>>(t, sos, emb, pval, pidx, xh, xl,
                                          Wih, bih, Whh, bhh,
                                          Wihh, Wihl, Whhh, Whhl,
                                          hf[p], hh[p], hl[p],
                                          hf[p ^ 1], hh[p ^ 1], hl[p ^ 1]);
      k_logctx<false><<<LCHN + CTXB, 512, 0, stream>>>(enc, W1, b1, W2, b2, encW1,
                                          Wo, bo, Woh, Wol,
                                          hf[p ^ 1], hh[p ^ 1], hl[p ^ 1],
                                          out + (size_t)t * BATCH * VOC,
                                          pval, pidx, xh, xl);
    }
  }
}

// Round 5
// 2964.882 us; speedup vs baseline: 1.1269x; 1.1269x over previous
//
#include <hip/hip_runtime.h>
#include <hip/hip_bf16.h>
#include <math.h>

typedef __bf16 bf16x8 __attribute__((ext_vector_type(8)));
typedef __bf16 bf16x4 __attribute__((ext_vector_type(4)));
typedef float f32x4 __attribute__((ext_vector_type(4)));

#define S_LEN 128
#define BATCH 32
#define E2C 1024
#define DH 512
#define AH 32
#define EMBD 256
#define VOC 32000
#define TMAX 48
#define LCHN 250     /* logits chunks: 128 vocab rows each */
#define CTXB 128     /* context blocks: 4 per batch, 256 elems each */

#define MFMA16(a, b, c) __builtin_amdgcn_mfma_f32_16x16x32_bf16((a), (b), (c), 0, 0, 0)

// ---- workspace layout (bytes) ----
#define OFF_HF0   0
#define OFF_HH0   65536
#define OFF_HL0   98304
#define OFF_HF1   131072
#define OFF_HH1   196608
#define OFF_HL1   229376
#define OFF_XH    262144            /* [32][1024] bf16 context hi */
#define OFF_XL    344064            /* [32][1024] bf16 context lo */
#define OFF_ENCW1 425984
#define OFF_PVAL  950272            /* 32 x 256 f32 */
#define OFF_PIDX  983040            /* 32 x 256 i32 */
#define OFF_WOH   1015808
#define OFF_WOL   33783808
#define OFF_WIHH  66551808
#define OFF_WIHL  70483968
#define OFF_WHHH  74416128
#define OFF_WHHL  75988992
#define WS_REQ    77561856ULL

// Split 8 consecutive f32 into bf16 hi + bf16 lo (x = hi + lo + O(2^-18 x)).
__device__ __forceinline__ void split8(const float* __restrict__ p,
                                       bf16x8& hi, bf16x8& lo) {
  const f32x4 v0 = *(const f32x4*)p;
  const f32x4 v1 = *(const f32x4*)(p + 4);
  float t[8] = {v0[0], v0[1], v0[2], v0[3], v1[0], v1[1], v1[2], v1[3]};
  #pragma unroll
  for (int i = 0; i < 8; i++) {
    const __bf16 h = (__bf16)t[i];
    hi[i] = h;
    lo[i] = (__bf16)(t[i] - (float)h);
  }
}

// ---------------------------------------------------------------------------
// K_init: zero the h-state block (hf0|hh0|hl0 = 131072 B = 32768 u32).
// ---------------------------------------------------------------------------
__global__ __launch_bounds__(256) void k_init(unsigned int* __restrict__ p) {
  p[blockIdx.x * 256 + threadIdx.x] = 0u;
}

// ---------------------------------------------------------------------------
// K0: encW1[s,b,j] = sum_k enc[s,b,k] * W1[j, DH+k]   (hoisted out of t-loop)
// ---------------------------------------------------------------------------
__global__ __launch_bounds__(256) void k_encw1(const float* __restrict__ enc,
                                               const float* __restrict__ W1,
                                               float* __restrict__ encW1) {
  __shared__ float el[E2C];
  __shared__ float red[256];
  const int tid = threadIdx.x;
  const int blk = blockIdx.x;                       // s*BATCH + b
  for (int i = 0; i < 4; i++)
    el[tid + i * 256] = enc[(size_t)blk * E2C + tid + i * 256];
  __syncthreads();
  const int j = tid >> 3, c = tid & 7;
  const float* wrow = W1 + (size_t)j * (DH + E2C) + DH;
  float p = 0.f;
  for (int k = c * 128; k < c * 128 + 128; k++) p += el[k] * wrow[k];
  red[tid] = p;
  __syncthreads();
  if (c < 4) red[tid] += red[tid + 4];
  __syncthreads();
  if (c < 2) red[tid] += red[tid + 2];
  __syncthreads();
  if (c == 0) encW1[(size_t)blk * AH + j] = red[tid] + red[tid + 1];
}

// ---------------------------------------------------------------------------
// K_split4: one-time f32 -> (bf16 hi, bf16 lo) split, 4 elements/thread.
// ---------------------------------------------------------------------------
__global__ __launch_bounds__(256) void k_split4(const float* __restrict__ src,
                                                __bf16* __restrict__ dh,
                                                __bf16* __restrict__ dl, int n4) {
  const int i = blockIdx.x * 256 + threadIdx.x;
  if (i >= n4) return;
  const f32x4 v = ((const f32x4*)src)[i];
  bf16x4 h4, l4;
  #pragma unroll
  for (int j = 0; j < 4; j++) {
    const float x = v[j];
    const __bf16 h = (__bf16)x;
    h4[j] = h;
    l4[j] = (__bf16)(x - (float)h);
  }
  *(bf16x4*)(dh + (size_t)i * 4) = h4;
  *(bf16x4*)(dl + (size_t)i * 4) = l4;
}

// ---------------------------------------------------------------------------
// ctx_block: attention context for one (batch, quarter); 256 threads.
// Exact round-3 k_attn phases B/C/D (bit-identical math).
//   bc = batch*4 + part; context quarter [part*256, part*256+256).
// ---------------------------------------------------------------------------
__device__ __forceinline__ void ctx_block(int bc, int tid,
    const float* __restrict__ enc,
    const float* __restrict__ W1, const float* __restrict__ b1,
    const float* __restrict__ W2, const float* __restrict__ b2,
    const float* __restrict__ encW1, const float* __restrict__ hf,
    __bf16* __restrict__ xh, __bf16* __restrict__ xl,
    float* hs, float* hw, float* sc, float* red) {
  const int b = bc >> 2;
  const int part = bc & 3;

  // Phase B: hW1[j] = h[b,:] . W1[j,0:DH] + b1[j]
  hs[tid] = hf[b * DH + tid];
  hs[tid + 256] = hf[b * DH + tid + 256];
  __syncthreads();
  {
    const int j = tid >> 3, c = tid & 7;
    const float* wrow = W1 + (size_t)j * (DH + E2C);
    float p = 0.f;
    for (int k = c * 64; k < c * 64 + 64; k++) p += hs[k] * wrow[k];
    red[tid] = p;
  }
  __syncthreads();
  if ((tid & 7) < 4) red[tid] += red[tid + 4];
  __syncthreads();
  if ((tid & 7) < 2) red[tid] += red[tid + 2];
  __syncthreads();
  if ((tid & 7) == 0) hw[tid >> 3] = red[tid] + red[tid + 1] + b1[tid >> 3];
  __syncthreads();

  // Phase C: scores + softmax over S
  float ex = 0.f;
  if (tid < S_LEN) {
    const float* ew = encW1 + ((size_t)tid * BATCH + b) * AH;
    float sum = b2[0];
    #pragma unroll
    for (int j = 0; j < AH; j++) {
      const float v = ew[j] + hw[j];
      sum += fmaxf(v, 0.f) * W2[j];
    }
    sc[tid] = sum;
  }
  __syncthreads();
  if (tid < 128) red[tid] = sc[tid];
  __syncthreads();
  for (int off = 64; off >= 1; off >>= 1) {
    if (tid < off) red[tid] = fmaxf(red[tid], red[tid + off]);
    __syncthreads();
  }
  const float mx = red[0];
  __syncthreads();
  if (tid < 128) { ex = expf(sc[tid] - mx); red[tid] = ex; }
  __syncthreads();
  for (int off = 64; off >= 1; off >>= 1) {
    if (tid < off) red[tid] += red[tid + off];
    __syncthreads();
  }
  const float ssum = red[0];
  if (tid < 128) sc[tid] = ex / ssum;
  __syncthreads();

  // Phase D: context quarter; 1 element/thread
  const int e0 = part * 256 + tid;
  float aa = 0.f;
  for (int s = 0; s < S_LEN; s++)
    aa += sc[s] * enc[((size_t)s * BATCH + b) * E2C + e0];
  const __bf16 ch = (__bf16)aa;
  xh[b * 1024 + e0] = ch;
  xl[b * 1024 + e0] = (__bf16)(aa - (float)ch);
}

// ---------------------------------------------------------------------------
// K_ctx0: initial context (t=0, h=0). Grid = 128 x 256.
// ---------------------------------------------------------------------------
__global__ __launch_bounds__(256) void k_ctx0(
    const float* __restrict__ enc,
    const float* __restrict__ W1, const float* __restrict__ b1,
    const float* __restrict__ W2, const float* __restrict__ b2,
    const float* __restrict__ encW1, const float* __restrict__ hf,
    __bf16* __restrict__ xh, __bf16* __restrict__ xl) {
  __shared__ float hs[DH];
  __shared__ float hw[AH];
  __shared__ float sc[S_LEN];
  __shared__ float red[256];
  ctx_block(blockIdx.x, threadIdx.x, enc, W1, b1, W2, b2, encW1, hf, xh, xl,
            hs, hw, sc, red);
}

// ---------------------------------------------------------------------------
// K2: GRU cell (verified round-4 version). Grid = 32 x 256.
// Prologue: final argmax over pval/pidx -> token ids; emb K-slab loaded
// directly from the table with split8 (bit-identical to staging).
// ---------------------------------------------------------------------------
template<bool PRE>
__global__ __launch_bounds__(256) void k_gru(int t,
    const int* __restrict__ sos, const float* __restrict__ emb,
    const float* __restrict__ pval, const int* __restrict__ pidx,
    const __bf16* __restrict__ xh, const __bf16* __restrict__ xl,
    const float* __restrict__ Wih, const float* __restrict__ bih,
    const float* __restrict__ Whh, const float* __restrict__ bhh,
    const __bf16* __restrict__ Wihh, const __bf16* __restrict__ Wihl,
    const __bf16* __restrict__ Whhh, const __bf16* __restrict__ Whhl,
    const float* __restrict__ hf_in, const __bf16* __restrict__ hh_in,
    const __bf16* __restrict__ hl_in,
    float* __restrict__ hf_out, __bf16* __restrict__ hh_out,
    __bf16* __restrict__ hl_out) {
  __shared__ float lds[4][8][256];
  __shared__ int ids[32];
  const int tid = threadIdx.x;

  // ---- prologue: token ids for this step ----
  if (t == 0) {
    if (tid < 32) {
      int id = sos[0];
      if (id < 0 || id >= VOC) id = 0;
      ids[tid] = id;
    }
  } else {
    float* sv = &lds[0][0][0];
    int*   si = (int*)&lds[1][0][0];
    const int b = tid >> 3, c0 = tid & 7;
    float bv = -INFINITY; int bi = 0x7fffffff;
    for (int c = c0; c < LCHN; c += 8) {
      const float v = pval[b * 256 + c]; const int ix = pidx[b * 256 + c];
      if (v > bv || (v == bv && ix < bi)) { bv = v; bi = ix; }
    }
    sv[tid] = bv; si[tid] = bi;
    __syncthreads();
    for (int off = 4; off >= 1; off >>= 1) {
      if (c0 < off) {
        const float ov = sv[tid + off]; const int oi = si[tid + off];
        if (ov > sv[tid] || (ov == sv[tid] && oi < si[tid])) { sv[tid] = ov; si[tid] = oi; }
      }
      __syncthreads();
    }
    if (c0 == 0) {
      int id = si[tid];
      if (id < 0 || id >= VOC) id = 0;
      ids[b] = id;
    }
  }
  __syncthreads();

  const int wv = tid >> 6;
  const int lane = tid & 63;
  const int q = lane >> 4;
  const int ln = lane & 15;
  const int d = blockIdx.x * 16 + ln;          // weight row (n index)
  const int id0 = ids[ln];
  const int id1 = ids[16 + ln];

  f32x4 acc[4][2];                             // t: 0=r 1=z 2=n_i 3=n_h; [mt]
  const f32x4 z4 = {0.f, 0.f, 0.f, 0.f};
  #pragma unroll
  for (int tt = 0; tt < 4; tt++) { acc[tt][0] = z4; acc[tt][1] = z4; }

  #pragma unroll
  for (int i = 0; i < 14; i++) {
    const int ka = wv * 32 + i * 128 + q * 8;
    bf16x8 ah0, al0, ah1, al1;
    if (i < 8) {                               // context from x
      ah0 = *(const bf16x8*)(xh + ln * 1024 + ka);
      ah1 = *(const bf16x8*)(xh + (16 + ln) * 1024 + ka);
      al0 = *(const bf16x8*)(xl + ln * 1024 + ka);
      al1 = *(const bf16x8*)(xl + (16 + ln) * 1024 + ka);
    } else if (i < 10) {                       // embedding, direct from table
      const int kb = ka - 1024;
      split8(emb + (size_t)id0 * EMBD + kb, ah0, al0);
      split8(emb + (size_t)id1 * EMBD + kb, ah1, al1);
    } else {                                   // hidden state
      const int kb = ka - 1280;
      ah0 = *(const bf16x8*)(hh_in + ln * 512 + kb);
      ah1 = *(const bf16x8*)(hh_in + (16 + ln) * 512 + kb);
      al0 = *(const bf16x8*)(hl_in + ln * 512 + kb);
      al1 = *(const bf16x8*)(hl_in + (16 + ln) * 512 + kb);
    }
    #pragma unroll
    for (int g = 0; g < 3; g++) {
      bf16x8 bh, bl;
      if (PRE) {
        if (i < 10) {
          bh = *(const bf16x8*)(Wihh + (size_t)(g * 512 + d) * 1280 + ka);
          bl = *(const bf16x8*)(Wihl + (size_t)(g * 512 + d) * 1280 + ka);
        } else {
          bh = *(const bf16x8*)(Whhh + (size_t)(g * 512 + d) * 512 + (ka - 1280));
          bl = *(const bf16x8*)(Whhl + (size_t)(g * 512 + d) * 512 + (ka - 1280));
        }
      } else {
        if (i < 10) split8(Wih + (size_t)(g * 512 + d) * 1280 + ka, bh, bl);
        else        split8(Whh + (size_t)(g * 512 + d) * 512 + (ka - 1280), bh, bl);
      }
      const int tt = (g < 2) ? g : ((i < 10) ? 2 : 3);
      acc[tt][0] = MFMA16(ah0, bh, acc[tt][0]);
      acc[tt][0] = MFMA16(al0, bh, acc[tt][0]);
      acc[tt][0] = MFMA16(ah0, bl, acc[tt][0]);
      acc[tt][1] = MFMA16(ah1, bh, acc[tt][1]);
      acc[tt][1] = MFMA16(al1, bh, acc[tt][1]);
      acc[tt][1] = MFMA16(ah1, bl, acc[tt][1]);
    }
  }

  // stage per-wave partials: tile tt2 = tt*2+mt, elem = row*16 + col
  #pragma unroll
  for (int tt = 0; tt < 4; tt++)
    #pragma unroll
    for (int mt = 0; mt < 2; mt++)
      #pragma unroll
      for (int r = 0; r < 4; r++)
        lds[wv][tt * 2 + mt][(q * 4 + r) * 16 + ln] = acc[tt][mt][r];
  __syncthreads();
  for (int idx = tid; idx < 8 * 256; idx += 256) {
    const int tt = idx >> 8, e = idx & 255;
    lds[0][tt][e] += lds[1][tt][e] + lds[2][tt][e] + lds[3][tt][e];
  }
  __syncthreads();

  // epilogue: (b, dd) pairs; D row = batch, col = d
  for (int u = tid; u < 512; u += 256) {
    const int b = u >> 4, dd = u & 15;
    const int mt = b >> 4;
    const int e = (b & 15) * 16 + dd;
    const int dg = blockIdx.x * 16 + dd;
    const float rp  = lds[0][0 * 2 + mt][e] + bih[dg]        + bhh[dg];
    const float zp  = lds[0][1 * 2 + mt][e] + bih[DH + dg]   + bhh[DH + dg];
    const float gin = lds[0][2 * 2 + mt][e] + bih[2 * DH + dg];
    const float ghn = lds[0][3 * 2 + mt][e] + bhh[2 * DH + dg];
    const float rg = 1.f / (1.f + expf(-rp));
    const float zg = 1.f / (1.f + expf(-zp));
    const float ng = tanhf(gin + rg * ghn);
    const float hp = hf_in[b * DH + dg];
    const float hn = (1.f - zg) * ng + zg * hp;
    hf_out[b * DH + dg] = hn;
    const __bf16 hi = (__bf16)hn;
    hh_out[b * DH + dg] = hi;
    hl_out[b * DH + dg] = (__bf16)(hn - (float)hi);
  }
}

// ---------------------------------------------------------------------------
// K3: merged logits + next-step context, 256 threads. Grid = 128 + 250.
//   blocks 0..127  : context(t+1) (short, scheduled first -> fully hidden)
//   blocks 128..377: logits, exact round-3 shape (128 rows, 2 tiles/wave,
//                    NT stores, per-chunk argmax partials).
// ---------------------------------------------------------------------------
template<bool PRE>
__global__ __launch_bounds__(256) void k_logctx(
    const float* __restrict__ enc,
    const float* __restrict__ W1, const float* __restrict__ b1,
    const float* __restrict__ W2, const float* __restrict__ b2,
    const float* __restrict__ encW1,
    const float* __restrict__ Wo, const float* __restrict__ bo,
    const __bf16* __restrict__ Woh, const __bf16* __restrict__ Wol,
    const float* __restrict__ hf, const __bf16* __restrict__ hh,
    const __bf16* __restrict__ hl,
    float* __restrict__ outp, float* __restrict__ pval, int* __restrict__ pidx,
    __bf16* __restrict__ xh, __bf16* __restrict__ xl) {
  __shared__ union {
    struct { float hs[DH]; float hw[AH]; float sc[S_LEN]; float red[256]; } c;
    struct { float lv[128]; int li[128]; } l;
  } sm;
  const int tid = threadIdx.x;

  if (blockIdx.x < CTXB) {           // ---- context path ----
    ctx_block(blockIdx.x, tid, enc, W1, b1, W2, b2, encW1, hf, xh, xl,
              sm.c.hs, sm.c.hw, sm.c.sc, sm.c.red);
    return;
  }
  const int chunk = blockIdx.x - CTXB;

  // ---- logits path (exact round-3 k_logits) ----
  const int w = tid >> 6;
  const int lane = tid & 63;
  const int quad = lane >> 4;
  const int ln = lane & 15;
  const int v0 = chunk * 128;

  f32x4 acc[2][2];
  const f32x4 z4 = {0.f, 0.f, 0.f, 0.f};
  #pragma unroll
  for (int m = 0; m < 2; m++)
    #pragma unroll
    for (int n = 0; n < 2; n++) acc[m][n] = z4;

  #pragma unroll 2
  for (int kk = 0; kk < 512; kk += 32) {
    const int ka = kk + quad * 8;
    const bf16x8 fh0 = *(const bf16x8*)(hh + ln * 512 + ka);
    const bf16x8 fh1 = *(const bf16x8*)(hh + (16 + ln) * 512 + ka);
    const bf16x8 fl0 = *(const bf16x8*)(hl + ln * 512 + ka);
    const bf16x8 fl1 = *(const bf16x8*)(hl + (16 + ln) * 512 + ka);
    #pragma unroll
    for (int nt = 0; nt < 2; nt++) {
      const int vr = v0 + (w * 2 + nt) * 16 + ln;
      bf16x8 bh, bl;
      if (PRE) {
        bh = *(const bf16x8*)(Woh + (size_t)vr * 512 + ka);
        bl = *(const bf16x8*)(Wol + (size_t)vr * 512 + ka);
      } else {
        split8(Wo + (size_t)vr * 512 + ka, bh, bl);
      }
      acc[0][nt] = MFMA16(fh0, bh, acc[0][nt]);
      acc[0][nt] = MFMA16(fl0, bh, acc[0][nt]);
      acc[0][nt] = MFMA16(fh0, bl, acc[0][nt]);
      acc[1][nt] = MFMA16(fh1, bh, acc[1][nt]);
      acc[1][nt] = MFMA16(fl1, bh, acc[1][nt]);
      acc[1][nt] = MFMA16(fh1, bl, acc[1][nt]);
    }
  }

  float bv[2][4]; int bi[2][4];
  #pragma unroll
  for (int m = 0; m < 2; m++)
    #pragma unroll
    for (int r = 0; r < 4; r++) { bv[m][r] = -INFINITY; bi[m][r] = 0x7fffffff; }

  #pragma unroll
  for (int nt = 0; nt < 2; nt++) {             // ascending v -> strict > keeps lowest idx
    const int v = v0 + (w * 2 + nt) * 16 + ln;
    const float bias = bo[v];
    #pragma unroll
    for (int mt = 0; mt < 2; mt++) {
      #pragma unroll
      for (int r = 0; r < 4; r++) {
        const float val = acc[mt][nt][r] + bias;
        const int b = mt * 16 + quad * 4 + r;
        __builtin_nontemporal_store(val, &outp[(size_t)b * VOC + v]);
        if (val > bv[mt][r]) { bv[mt][r] = val; bi[mt][r] = v; }
      }
    }
  }
  // reduce over the 16 lanes (ln) holding different v
  #pragma unroll
  for (int m = 1; m < 16; m <<= 1) {
    #pragma unroll
    for (int mt = 0; mt < 2; mt++) {
      #pragma unroll
      for (int r = 0; r < 4; r++) {
        const float ov = __shfl_xor(bv[mt][r], m, 64);
        const int oi = __shfl_xor(bi[mt][r], m, 64);
        if (ov > bv[mt][r] || (ov == bv[mt][r] && oi < bi[mt][r])) {
          bv[mt][r] = ov; bi[mt][r] = oi;
        }
      }
    }
  }
  if (ln == 0) {
    #pragma unroll
    for (int mt = 0; mt < 2; mt++)
      for (int r = 0; r < 4; r++) {
        const int b = mt * 16 + quad * 4 + r;
        sm.l.lv[w * 32 + b] = bv[mt][r];
        sm.l.li[w * 32 + b] = bi[mt][r];
      }
  }
  __syncthreads();
  if (tid < 32) {
    float bbv = sm.l.lv[tid]; int bbi = sm.l.li[tid];
    for (int w2 = 1; w2 < 4; w2++) {           // ascending wave -> ascending v
      const float ov = sm.l.lv[w2 * 32 + tid]; const int oi = sm.l.li[w2 * 32 + tid];
      if (ov > bbv || (ov == bbv && oi < bbi)) { bbv = ov; bbi = oi; }
    }
    pval[tid * 256 + chunk] = bbv;
    pidx[tid * 256 + chunk] = bbi;
  }
}

// ---------------------------------------------------------------------------
extern "C" void kernel_launch(void* const* d_in, const int* in_sizes, int n_in,
                              void* d_out, int out_size, void* d_ws, size_t ws_size,
                              hipStream_t stream) {
  const float* enc = (const float*)d_in[0];
  const int* sos = (const int*)d_in[2];
  const float* emb = (const float*)d_in[3];
  const float* W1 = (const float*)d_in[4];
  const float* b1 = (const float*)d_in[5];
  const float* W2 = (const float*)d_in[6];
  const float* b2 = (const float*)d_in[7];
  const float* Wih = (const float*)d_in[8];
  const float* bih = (const float*)d_in[9];
  const float* Whh = (const float*)d_in[10];
  const float* bhh = (const float*)d_in[11];
  const float* Wo = (const float*)d_in[12];
  const float* bo = (const float*)d_in[13];

  char* ws = (char*)d_ws;
  float* hf[2]  = {(float*)(ws + OFF_HF0),  (float*)(ws + OFF_HF1)};
  __bf16* hh[2] = {(__bf16*)(ws + OFF_HH0), (__bf16*)(ws + OFF_HH1)};
  __bf16* hl[2] = {(__bf16*)(ws + OFF_HL0), (__bf16*)(ws + OFF_HL1)};
  __bf16* xh = (__bf16*)(ws + OFF_XH);
  __bf16* xl = (__bf16*)(ws + OFF_XL);
  float* encW1 = (float*)(ws + OFF_ENCW1);
  float* pval = (float*)(ws + OFF_PVAL);
  int* pidx = (int*)(ws + OFF_PIDX);
  __bf16* Woh  = (__bf16*)(ws + OFF_WOH);
  __bf16* Wol  = (__bf16*)(ws + OFF_WOL);
  __bf16* Wihh = (__bf16*)(ws + OFF_WIHH);
  __bf16* Wihl = (__bf16*)(ws + OFF_WIHL);
  __bf16* Whhh = (__bf16*)(ws + OFF_WHHH);
  __bf16* Whhl = (__bf16*)(ws + OFF_WHHL);

  k_init<<<128, 256, 0, stream>>>((unsigned int*)ws);   // h state = 0
  k_encw1<<<S_LEN * BATCH, 256, 0, stream>>>(enc, W1, encW1);

  float* out = (float*)d_out;
  const bool pre = (ws_size >= WS_REQ);
  if (pre) {
    k_split4<<<16000, 256, 0, stream>>>(Wo,  Woh,  Wol,  4096000);
    k_split4<<<1920,  256, 0, stream>>>(Wih, Wihh, Wihl, 491520);
    k_split4<<<768,   256, 0, stream>>>(Whh, Whhh, Whhl, 196608);
  }
  k_ctx0<<<CTXB, 256, 0, stream>>>(enc, W1, b1, W2, b2, encW1, hf[0], xh, xl);

  for (int t = 0; t < TMAX; t++) {
    const int p = t & 1;
    if (pre) {
      k_gru<true><<<32, 256, 0, stream>>>(t, sos, emb, pval, pidx, xh, xl,
                                          Wih, bih, Whh, bhh,
                                          Wihh, Wihl, Whhh, Whhl,
                                          hf[p], hh[p], hl[p],
                                          hf[p ^ 1], hh[p ^ 1], hl[p ^ 1]);
      k_logctx<true><<<CTXB + LCHN, 256, 0, stream>>>(enc, W1, b1, W2, b2, encW1,
                                          Wo, bo, Woh, Wol,
                                          hf[p ^ 1], hh[p ^ 1], hl[p ^ 1],
                                          out + (size_t)t * BATCH * VOC,
                                          pval, pidx, xh, xl);
    } else {
      k_gru<false><<<32, 256, 0, stream>>>(t, sos, emb, pval, pidx, xh, xl,
                                          Wih, bih, Whh, bhh,
                                          Wihh, Wihl, Whhh, Whhl,
                                          hf[p], hh[p], hl[p],
                                          hf[p ^ 1], hh[p ^ 1], hl[p ^ 1]);
      k_logctx<false><<<CTXB + LCHN, 256, 0, stream>>>(enc, W1, b1, W2, b2, encW1,
                                          Wo, bo, Woh, Wol,
                                          hf[p ^ 1], hh[p ^ 1], hl[p ^ 1],
                                          out + (size_t)t * BATCH * VOC,
                                          pval, pidx, xh, xl);
    }
  }
}